// Round 1
// baseline (257.080 us; speedup 1.0000x reference)
//
#include <hip/hip_runtime.h>

// Pre-emphasis IIR: out[t] = y[t] + 0.85*out[t-1], shift SKIP=91, scale 32768,
// clip, astype(int16) (trunc toward zero); harness reads d_out as int32.
//
// R5 -> R6: R5's counters showed NOTHING saturated (HBM 32%, VALU 22%, LDS
// ~35% incl. 4.85M conflict cycles) at occupancy 71% with VGPR_Count=16 ->
// latency-bound and register-starved: 22 serialized ds_read_b128 + 87-deep
// FMA chain + 3 barriers per block. R6 deletes the input LDS staging: each
// thread reads its 88 contiguous floats directly from global as 22 x float4
// (warm-up overlap between lanes is L1-served: each 64B line touched 4x by
// the same wave). LDS is now only the 16KB output store-bounce, 1 barrier.
// __launch_bounds__(256,8) keeps 8 blk/CU while giving the scheduler VGPRs
// to pipeline global loads under the dependent FMA chain.

#define BLOCK   256
#define CH      16
#define TILE    (BLOCK * CH)        // 4096
#define SKIP    91
#define WARM    71                  // tStart = tileBase + 20 (16B-aligned)
#define COEF    0.85f
#define NREAD   88                  // 71 warm-up + 16 outputs + 1 spare = 22 float4
#define PAD4(p) ((p) + 4 * ((p) >> 5))   // 4-aligned p stays 16B-aligned
#define LDS_F   4608                // > PAD4(4092)+4 = 4604; 18 KB -> 8 blk/CU

typedef int v4i __attribute__((ext_vector_type(4)));

__global__ __launch_bounds__(BLOCK, 8) void preemph_kernel(
        const float* __restrict__ sig, int* __restrict__ out, int n) {
    __shared__ float lds[LDS_F];
    const int  tid      = threadIdx.x;
    const long tileBase = (long)blockIdx.x * TILE;
    const long tStart   = tileBase + (SKIP - WARM);   // tileBase + 20
    const long g0       = tStart + (long)tid * CH;    // 16B-aligned

    float acc = 0.f;
    int   res[CH];

    // Fast path unless this block's reads can run past the array end
    // (only the last block: reads extend 92 floats into the next tile).
    const bool safe = (tStart + (long)(BLOCK - 1) * CH + NREAD) <= (long)n;

    if (safe) {
        const float4* __restrict__ p = reinterpret_cast<const float4*>(sig + g0);
#pragma unroll
        for (int k = 0; k < NREAD / 4; ++k) {
            float4 v = p[k];
#pragma unroll
            for (int c = 0; c < 4; ++c) {
                const int e = 4 * k + c;              // compile-time
                float x = (c == 0) ? v.x : (c == 1) ? v.y : (c == 2) ? v.z : v.w;
                if (e < WARM) {
                    acc = fmaf(acc, COEF, x);
                } else if (e < WARM + CH) {
                    acc = fmaf(acc, COEF, x);
                    float s = acc * 32768.f;
                    s = fminf(fmaxf(s, -32768.f), 32767.f);
                    res[e - WARM] = (int)s;           // trunc toward zero
                }
            }
        }
    } else {
        // Last block only: fully unrolled so res[] stays in registers
        // (runtime-indexed arrays would spill to scratch).
#pragma unroll
        for (int e = 0; e < WARM + CH; ++e) {
            long g = g0 + e;
            float x = (g < (long)n) ? sig[g] : 0.f;
            acc = fmaf(acc, COEF, x);
            if (e >= WARM) {
                float s = acc * 32768.f;
                s = fminf(fmaxf(s, -32768.f), 32767.f);
                res[e - WARM] = (int)s;
            }
        }
    }

    // Tail: outputs >= n-SKIP are zero-padded.
    const long oBase = tileBase + (long)tid * CH;
    const long oLim  = (long)n - SKIP;
#pragma unroll
    for (int j = 0; j < CH; ++j)
        if (oBase + j >= oLim) res[j] = 0;

    // Store-bounce: int results -> LDS via 4 x ds_write_b128 (padded layout),
    // then linear ds_read_b128 -> coalesced nontemporal int4 stores.
    float4* const l4 = reinterpret_cast<float4*>(lds);
    const int p0 = tid * CH;
#pragma unroll
    for (int k = 0; k < 4; ++k) {
        float4 v;
        v.x = __int_as_float(res[4 * k + 0]);
        v.y = __int_as_float(res[4 * k + 1]);
        v.z = __int_as_float(res[4 * k + 2]);
        v.w = __int_as_float(res[4 * k + 3]);
        l4[PAD4(p0 + 4 * k) >> 2] = v;
    }
    __syncthreads();

#pragma unroll
    for (int k = 0; k < 4; ++k) {
        int  off = k * (BLOCK * 4) + tid * 4;         // TILE = 4*1024 exactly
        long o   = tileBase + off;
        float4 v = l4[PAD4(off) >> 2];
        v4i iv;
        iv.x = __float_as_int(v.x);
        iv.y = __float_as_int(v.y);
        iv.z = __float_as_int(v.z);
        iv.w = __float_as_int(v.w);
        if (o + 3 < (long)n) {
            __builtin_nontemporal_store(iv, reinterpret_cast<v4i*>(out + o));
        } else {
            if (o + 0 < (long)n) out[o + 0] = iv.x;
            if (o + 1 < (long)n) out[o + 1] = iv.y;
            if (o + 2 < (long)n) out[o + 2] = iv.z;
        }
    }
}

extern "C" void kernel_launch(void* const* d_in, const int* in_sizes, int n_in,
                              void* d_out, int out_size, void* d_ws, size_t ws_size,
                              hipStream_t stream) {
    const float* sig = (const float*)d_in[0];
    int* out = (int*)d_out;
    int n = in_sizes[0];
    int grid = (int)(((long)n + TILE - 1) / TILE);
    preemph_kernel<<<grid, BLOCK, 0, stream>>>(sig, out, n);
}

// Round 2
// 235.491 us; speedup vs baseline: 1.0917x; 1.0917x over previous
//
#include <hip/hip_runtime.h>

// Pre-emphasis IIR: out[t] = y[t] + 0.85*out[t-1], shift SKIP=91, scale 32768,
// clip, astype(int16) (trunc toward zero); harness reads d_out as int32.
//
// R6 -> R7: R6 (direct per-thread-contiguous global reads) regressed 79->104us:
// stride-64B lanes make every dwordx4 touch 64 distinct lines (4x transaction
// amplification) -> TA-bound. R7 resolves the coalescing-vs-IIR tension
// algebraically: each lane owns 4 contiguous floats (float4 = perfectly
// coalesced), cross-lane composition via wave Hillis-Steele scan of the
// affine maps. Decay per lane is uniform c^4 so the scan multipliers are
// compile-time constants: 5 x (shfl_up + fma). No LDS storage, no barriers,
// no per-thread warm-up (one 256-sample warm chunk per 4096-output wave
// segment = 6% extra loads, carry history c^256 ~ exact). The SKIP%4=3
// misalignment is absorbed in registers: store int4 = {shfl_up(prev elem3),
// own elems 0..2}; lane 0 uses the converted carry. Loads+stores both
// aligned & coalesced.

#define BLOCK   256
#define SKIP    91
#define COEF    0.85f
#define CHUNK_N 256                  // elements per wave chunk (64 lanes x 4)
#define CHUNKS  16                   // main chunks per wave
#define SEG     (CHUNKS * CHUNK_N)   // 4096 outputs per wave
#define WPB     (BLOCK / 64)         // 4 waves per block
#define TILE    (WPB * SEG)          // 16384 outputs per block

typedef int v4i __attribute__((ext_vector_type(4)));

__device__ __forceinline__ int cvt16(float v) {
    float s = v * 32768.f;
    s = fminf(fmaxf(s, -32768.f), 32767.f);   // fuses to v_med3_f32
    return (int)s;                            // trunc toward zero
}

__device__ __forceinline__ float4 ld_chunk(const float* __restrict__ sig,
                                           long yb, long n, bool safe) {
    if (safe) return *reinterpret_cast<const float4*>(sig + yb);
    float4 x;
    x.x = (yb + 0 >= 0 && yb + 0 < n) ? sig[yb + 0] : 0.f;
    x.y = (yb + 1 >= 0 && yb + 1 < n) ? sig[yb + 1] : 0.f;
    x.z = (yb + 2 >= 0 && yb + 2 < n) ? sig[yb + 2] : 0.f;
    x.w = (yb + 3 >= 0 && yb + 3 < n) ? sig[yb + 3] : 0.f;
    return x;
}

__global__ __launch_bounds__(BLOCK, 8) void preemph_kernel(
        const float* __restrict__ sig, int* __restrict__ out, int n) {
    const long ln   = n;
    const int  lane = threadIdx.x & 63;
    const long segBase = (long)blockIdx.x * TILE + (long)(threadIdx.x >> 6) * SEG;
    if (segBase >= ln) return;

    // scan-step multipliers: c^(4*2^d) — compile-time constants.
    const float K1  = COEF * COEF * COEF * COEF;   // c^4
    const float K2  = K1 * K1;                      // c^8
    const float K4  = K2 * K2;                      // c^16
    const float K8  = K4 * K4;                      // c^32
    const float K16 = K8 * K8;                      // c^64
    // (d=32 step weight c^128 ~ 9e-10: below fp32 noise at this scale — dropped)
    const float C1 = COEF, C2 = COEF * COEF, C3 = C2 * COEF, C4 = K1;
    // per-lane carry weight c^(4*(lane+1))
    const float wpow = exp2f((float)(lane + 1) * (4.0f * -0.23446525109f)); // log2(0.85)

    float s0, s1, s2, s3;
    // wave scan: returns t[i] = IIR value at lane i elem3 assuming zero state
    // at window start; also fills the lane-local inclusive scan s0..s3.
    auto wscan = [&](const float4& x) -> float {
        s0 = x.x;
        s1 = fmaf(s0, COEF, x.y);
        s2 = fmaf(s1, COEF, x.z);
        s3 = fmaf(s2, COEF, x.w);
        float t = s3, u;
        u = __shfl_up(t, 1, 64);  t = (lane >= 1)  ? fmaf(u, K1,  t) : t;
        u = __shfl_up(t, 2, 64);  t = (lane >= 2)  ? fmaf(u, K2,  t) : t;
        u = __shfl_up(t, 4, 64);  t = (lane >= 4)  ? fmaf(u, K4,  t) : t;
        u = __shfl_up(t, 8, 64);  t = (lane >= 8)  ? fmaf(u, K8,  t) : t;
        u = __shfl_up(t, 16, 64); t = (lane >= 16) ? fmaf(u, K16, t) : t;
        return t;
    };

    // ---- warm-up chunk: y[segBase-164 .. segBase+92) -> carry at y=segBase+91.
    // Negative indices zero-filled == exact (IIR from zero state).
    const bool warmSafe = (segBase >= 164);
    float4 xw = ld_chunk(sig, segBase - 164 + 4 * (long)lane, ln, warmSafe);

    // prefetch main chunk 0: y[segBase+92 .. +256)
    bool  csafe0 = (segBase + (SKIP + 1) + CHUNK_N) <= ln;
    float4 xc = ld_chunk(sig, segBase + (SKIP + 1) + 4 * (long)lane, ln, csafe0);

    float tw   = wscan(xw);
    float y_in = __shfl(tw, 63, 64);   // carry: scan value at y = segBase+91

    const long oLim = ln - SKIP;

#pragma unroll 4
    for (int c = 0; c < CHUNKS; ++c) {
        const long o0 = segBase + (long)c * CHUNK_N;   // chunk output base
        if (o0 >= ln) break;

        // prefetch next chunk while this one computes
        float4 xn;
        if (c + 1 < CHUNKS) {
            long yn    = segBase + (SKIP + 1) + (long)(c + 1) * CHUNK_N;
            bool snext = (yn + CHUNK_N) <= ln;
            xn = ld_chunk(sig, yn + 4 * (long)lane, ln, snext);
        }

        float t = wscan(xc);
        float L = fmaf(wpow, y_in, t);        // + carry contribution
        float p = __shfl_up(L, 1, 64);        // incoming prefix for this lane
        if (lane == 0) p = y_in;

        float o0f = fmaf(p, C1, s0);
        float o1f = fmaf(p, C2, s1);
        float o2f = fmaf(p, C3, s2);
        float o3f = fmaf(p, C4, s3);
        int i0 = cvt16(o0f), i1 = cvt16(o1f), i2 = cvt16(o2f);
        int i3 = cvt16(o3f);

        // realign by SKIP%4=3: slot0 = prev lane's elem3 (lane0: the carry)
        int prv = __shfl_up(i3, 1, 64);
        if (lane == 0) prv = cvt16(y_in);
        v4i iv;
        iv.x = prv; iv.y = i0; iv.z = i1; iv.w = i2;

        y_in = __shfl(L, 63, 64);             // carry for next chunk

        const long ob = o0 + 4 * (long)lane;
        if (o0 + CHUNK_N > oLim) {            // zero-pad tail outputs
            if (ob + 0 >= oLim) iv.x = 0;
            if (ob + 1 >= oLim) iv.y = 0;
            if (ob + 2 >= oLim) iv.z = 0;
            if (ob + 3 >= oLim) iv.w = 0;
        }
        if (o0 + CHUNK_N <= ln) {
            __builtin_nontemporal_store(iv, reinterpret_cast<v4i*>(out + ob));
        } else {
            if (ob + 0 < ln) out[ob + 0] = iv.x;
            if (ob + 1 < ln) out[ob + 1] = iv.y;
            if (ob + 2 < ln) out[ob + 2] = iv.z;
            if (ob + 3 < ln) out[ob + 3] = iv.w;
        }
        xc = xn;
    }
}

extern "C" void kernel_launch(void* const* d_in, const int* in_sizes, int n_in,
                              void* d_out, int out_size, void* d_ws, size_t ws_size,
                              hipStream_t stream) {
    const float* sig = (const float*)d_in[0];
    int* out = (int*)d_out;
    int n = in_sizes[0];
    int grid = (int)(((long)n + TILE - 1) / TILE);
    preemph_kernel<<<grid, BLOCK, 0, stream>>>(sig, out, n);
}

// Round 3
// 235.424 us; speedup vs baseline: 1.0920x; 1.0003x over previous
//
#include <hip/hip_runtime.h>

// Pre-emphasis IIR: out[t] = y[t] + 0.85*out[t-1], shift SKIP=91, scale 32768,
// clip, astype(int16) (trunc toward zero); harness reads d_out as int32.
//
// R7 -> R8: R7 (wave affine-scan, zero LDS, zero conflicts) landed at the
// same ~80us / ~2.5 TB/s plateau as R5 with NOTHING saturated (VALU 13%,
// occupancy 68%, VGPR=24). Little's law: 2.5 TB/s needs only ~4KB/CU in
// flight -> the plateau is MLP starvation: prefetch depth 1 + carry chain
// means each wave has ~0-1 outstanding loads. R8 batch-loads the wave's
// ENTIRE segment (8 chunks x dwordx4, all independent, issued back-to-back)
// into registers before computing: 8KB/wave x 32 waves/CU = 256KB/CU in
// flight. Scan math, carry realign, NT stores identical to R7.

#define BLOCK   256
#define SKIP    91
#define COEF    0.85f
#define CHUNK_N 256                  // elements per wave chunk (64 lanes x 4)
#define CHUNKS  8                    // main chunks per wave (batch-loaded)
#define SEG     (CHUNKS * CHUNK_N)   // 2048 outputs per wave
#define WPB     (BLOCK / 64)         // 4 waves per block
#define TILE    (WPB * SEG)          // 8192 outputs per block

typedef int v4i __attribute__((ext_vector_type(4)));

__device__ __forceinline__ int cvt16(float v) {
    float s = v * 32768.f;
    s = fminf(fmaxf(s, -32768.f), 32767.f);   // fuses to v_med3_f32
    return (int)s;                            // trunc toward zero
}

__device__ __forceinline__ float4 ld_chunk(const float* __restrict__ sig,
                                           long yb, long n, bool safe) {
    if (safe) return *reinterpret_cast<const float4*>(sig + yb);
    float4 x;
    x.x = (yb + 0 >= 0 && yb + 0 < n) ? sig[yb + 0] : 0.f;
    x.y = (yb + 1 >= 0 && yb + 1 < n) ? sig[yb + 1] : 0.f;
    x.z = (yb + 2 >= 0 && yb + 2 < n) ? sig[yb + 2] : 0.f;
    x.w = (yb + 3 >= 0 && yb + 3 < n) ? sig[yb + 3] : 0.f;
    return x;
}

__global__ __launch_bounds__(BLOCK, 8) void preemph_kernel(
        const float* __restrict__ sig, int* __restrict__ out, int n) {
    const long ln   = n;
    const int  lane = threadIdx.x & 63;
    const long segBase = (long)blockIdx.x * TILE + (long)(threadIdx.x >> 6) * SEG;
    if (segBase >= ln) return;

    // scan-step multipliers: c^(4*2^d) — compile-time constants.
    const float K1  = COEF * COEF * COEF * COEF;   // c^4
    const float K2  = K1 * K1;                      // c^8
    const float K4  = K2 * K2;                      // c^16
    const float K8  = K4 * K4;                      // c^32
    const float K16 = K8 * K8;                      // c^64
    // (d=32 step weight c^128 ~ 9e-10: below fp32 noise at this scale — dropped)
    const float C1 = COEF, C2 = COEF * COEF, C3 = C2 * COEF, C4 = K1;
    // per-lane carry weight c^(4*(lane+1))
    const float wpow = exp2f((float)(lane + 1) * (4.0f * -0.23446525109f)); // log2(0.85)

    float s0, s1, s2, s3;
    // wave scan: returns t[i] = IIR value at lane i elem3 assuming zero state
    // at window start; also fills the lane-local inclusive scan s0..s3.
    auto wscan = [&](const float4& x) -> float {
        s0 = x.x;
        s1 = fmaf(s0, COEF, x.y);
        s2 = fmaf(s1, COEF, x.z);
        s3 = fmaf(s2, COEF, x.w);
        float t = s3, u;
        u = __shfl_up(t, 1, 64);  t = (lane >= 1)  ? fmaf(u, K1,  t) : t;
        u = __shfl_up(t, 2, 64);  t = (lane >= 2)  ? fmaf(u, K2,  t) : t;
        u = __shfl_up(t, 4, 64);  t = (lane >= 4)  ? fmaf(u, K4,  t) : t;
        u = __shfl_up(t, 8, 64);  t = (lane >= 8)  ? fmaf(u, K8,  t) : t;
        u = __shfl_up(t, 16, 64); t = (lane >= 16) ? fmaf(u, K16, t) : t;
        return t;
    };

    // ---- Batch-issue ALL loads first: warm chunk + 8 main chunks, all
    // independent dwordx4 -> 9 outstanding VMEM ops per wave at peak.
    const bool warmSafe = (segBase >= 164);
    float4 xw = ld_chunk(sig, segBase - 164 + 4 * (long)lane, ln, warmSafe);

    float4 xs[CHUNKS];
#pragma unroll
    for (int c = 0; c < CHUNKS; ++c) {
        long yb   = segBase + (SKIP + 1) + (long)c * CHUNK_N;
        bool safe = (yb + CHUNK_N) <= ln;
        xs[c] = ld_chunk(sig, yb + 4 * (long)lane, ln, safe);
    }

    // warm-up: y[segBase-164 .. segBase+92) -> carry at y = segBase+91.
    // Negative indices zero-filled == exact (IIR from zero state).
    float tw   = wscan(xw);
    float y_in = __shfl(tw, 63, 64);

    const long oLim = ln - SKIP;

#pragma unroll
    for (int c = 0; c < CHUNKS; ++c) {
        const long o0 = segBase + (long)c * CHUNK_N;   // chunk output base
        if (o0 >= ln) break;

        float t = wscan(xs[c]);
        float L = fmaf(wpow, y_in, t);        // + carry contribution
        float p = __shfl_up(L, 1, 64);        // incoming prefix for this lane
        if (lane == 0) p = y_in;

        float o0f = fmaf(p, C1, s0);
        float o1f = fmaf(p, C2, s1);
        float o2f = fmaf(p, C3, s2);
        float o3f = fmaf(p, C4, s3);
        int i0 = cvt16(o0f), i1 = cvt16(o1f), i2 = cvt16(o2f);
        int i3 = cvt16(o3f);

        // realign by SKIP%4=3: slot0 = prev lane's elem3 (lane0: the carry)
        int prv = __shfl_up(i3, 1, 64);
        if (lane == 0) prv = cvt16(y_in);
        v4i iv;
        iv.x = prv; iv.y = i0; iv.z = i1; iv.w = i2;

        y_in = __shfl(L, 63, 64);             // carry for next chunk

        const long ob = o0 + 4 * (long)lane;
        if (o0 + CHUNK_N > oLim) {            // zero-pad tail outputs
            if (ob + 0 >= oLim) iv.x = 0;
            if (ob + 1 >= oLim) iv.y = 0;
            if (ob + 2 >= oLim) iv.z = 0;
            if (ob + 3 >= oLim) iv.w = 0;
        }
        if (o0 + CHUNK_N <= ln) {
            __builtin_nontemporal_store(iv, reinterpret_cast<v4i*>(out + ob));
        } else {
            if (ob + 0 < ln) out[ob + 0] = iv.x;
            if (ob + 1 < ln) out[ob + 1] = iv.y;
            if (ob + 2 < ln) out[ob + 2] = iv.z;
            if (ob + 3 < ln) out[ob + 3] = iv.w;
        }
    }
}

extern "C" void kernel_launch(void* const* d_in, const int* in_sizes, int n_in,
                              void* d_out, int out_size, void* d_ws, size_t ws_size,
                              hipStream_t stream) {
    const float* sig = (const float*)d_in[0];
    int* out = (int*)d_out;
    int n = in_sizes[0];
    int grid = (int)(((long)n + TILE - 1) / TILE);
    preemph_kernel<<<grid, BLOCK, 0, stream>>>(sig, out, n);
}

// Round 4
// 229.646 us; speedup vs baseline: 1.1195x; 1.0252x over previous
//
#include <hip/hip_runtime.h>

// Pre-emphasis IIR: out[t] = y[t] + 0.85*out[t-1], shift SKIP=91, scale 32768,
// clip, astype(int16) (trunc toward zero); harness reads d_out as int32.
//
// R8 -> R9: R8's batch-load was DEFEATED by the compiler: per-chunk runtime
// `safe` branches put the 9 loads in divergent control flow -> xs[] spilled
// to scratch (VGPR stuck at 32, WRITE_SIZE inflated 134->159 MB, FETCH +13MB
// = spill/fill traffic), dispatch regressed to 90us. MLP theory never ran.
// R9 hoists ALL bounds checks into one wave-uniform `fast` flag: interior
// waves (4094/4096 blocks) execute 9 unconditional back-to-back
// global_load_dwordx4 (shared base + imm offsets), no tail checks,
// unconditional NT stores. Boundary waves take a generic if-constexpr path.
// Target: 9-deep MLP/wave x 8 waves/SIMD -> fill the HBM queue.

#define BLOCK   256
#define SKIP    91
#define COEF    0.85f
#define CHUNK_N 256                  // elements per wave chunk (64 lanes x 4)
#define CHUNKS  8                    // main chunks per wave (batch-loaded)
#define SEG     (CHUNKS * CHUNK_N)   // 2048 outputs per wave
#define WPB     (BLOCK / 64)         // 4 waves per block
#define TILE    (WPB * SEG)          // 8192 outputs per block

typedef int v4i __attribute__((ext_vector_type(4)));

__device__ __forceinline__ int cvt16(float v) {
    float s = v * 32768.f;
    s = fminf(fmaxf(s, -32768.f), 32767.f);   // fuses to v_med3_f32
    return (int)s;                            // trunc toward zero
}

__device__ __forceinline__ float4 ld_guard(const float* __restrict__ sig,
                                           long yb, long n) {
    float4 x;
    x.x = (yb + 0 >= 0 && yb + 0 < n) ? sig[yb + 0] : 0.f;
    x.y = (yb + 1 >= 0 && yb + 1 < n) ? sig[yb + 1] : 0.f;
    x.z = (yb + 2 >= 0 && yb + 2 < n) ? sig[yb + 2] : 0.f;
    x.w = (yb + 3 >= 0 && yb + 3 < n) ? sig[yb + 3] : 0.f;
    return x;
}

template <bool FAST>
__device__ __forceinline__ void run_seg(const float* __restrict__ sig,
                                        int* __restrict__ out,
                                        long segBase, long ln, int lane) {
    // scan-step multipliers: c^(4*2^d) — compile-time constants.
    const float K1  = COEF * COEF * COEF * COEF;   // c^4
    const float K2  = K1 * K1;                      // c^8
    const float K4  = K2 * K2;                      // c^16
    const float K8  = K4 * K4;                      // c^32
    const float K16 = K8 * K8;                      // c^64
    // (d=32 step weight c^128 ~ 9e-10: below fp32 noise — dropped)
    const float C1 = COEF, C2 = COEF * COEF, C3 = C2 * COEF, C4 = K1;
    // per-lane carry weight c^(4*(lane+1))
    const float wpow = exp2f((float)(lane + 1) * (4.0f * -0.23446525109f)); // log2(0.85)

    float s0, s1, s2, s3;
    // wave scan: t[i] = IIR value at lane i elem3 from zero state at window
    // start; also leaves the lane-local inclusive scan in s0..s3.
    auto wscan = [&](const float4& x) -> float {
        s0 = x.x;
        s1 = fmaf(s0, COEF, x.y);
        s2 = fmaf(s1, COEF, x.z);
        s3 = fmaf(s2, COEF, x.w);
        float t = s3, u;
        u = __shfl_up(t, 1, 64);  t = (lane >= 1)  ? fmaf(u, K1,  t) : t;
        u = __shfl_up(t, 2, 64);  t = (lane >= 2)  ? fmaf(u, K2,  t) : t;
        u = __shfl_up(t, 4, 64);  t = (lane >= 4)  ? fmaf(u, K4,  t) : t;
        u = __shfl_up(t, 8, 64);  t = (lane >= 8)  ? fmaf(u, K8,  t) : t;
        u = __shfl_up(t, 16, 64); t = (lane >= 16) ? fmaf(u, K16, t) : t;
        return t;
    };

    // ---- Batch-issue ALL loads: warm chunk + CHUNKS main chunks.
    // FAST path: zero control flow between loads -> back-to-back dwordx4.
    float4 xw, xs[CHUNKS];
    if constexpr (FAST) {
        const float* base = sig + segBase + 4 * (long)lane;   // 16B-aligned
        xw = *reinterpret_cast<const float4*>(base - 164);
#pragma unroll
        for (int c = 0; c < CHUNKS; ++c)
            xs[c] = *reinterpret_cast<const float4*>(base + (SKIP + 1) + c * CHUNK_N);
    } else {
        xw = ld_guard(sig, segBase - 164 + 4 * (long)lane, ln);
#pragma unroll
        for (int c = 0; c < CHUNKS; ++c)
            xs[c] = ld_guard(sig, segBase + (SKIP + 1) + (long)c * CHUNK_N
                                  + 4 * (long)lane, ln);
    }

    // warm-up: y[segBase-164 .. segBase+92) -> carry at y = segBase+91.
    // Negative indices zero-filled == exact (IIR from zero state).
    float tw   = wscan(xw);
    float y_in = __shfl(tw, 63, 64);

    const long oLim = ln - SKIP;

#pragma unroll
    for (int c = 0; c < CHUNKS; ++c) {
        const long o0 = segBase + (long)c * CHUNK_N;   // chunk output base

        float t = wscan(xs[c]);
        float L = fmaf(wpow, y_in, t);        // + carry contribution
        float p = __shfl_up(L, 1, 64);        // incoming prefix for this lane
        if (lane == 0) p = y_in;

        float o0f = fmaf(p, C1, s0);
        float o1f = fmaf(p, C2, s1);
        float o2f = fmaf(p, C3, s2);
        float o3f = fmaf(p, C4, s3);
        int i0 = cvt16(o0f), i1 = cvt16(o1f), i2 = cvt16(o2f);
        int i3 = cvt16(o3f);

        // realign by SKIP%4=3: slot0 = prev lane's elem3 (lane0: the carry)
        int prv = __shfl_up(i3, 1, 64);
        if (lane == 0) prv = cvt16(y_in);
        v4i iv;
        iv.x = prv; iv.y = i0; iv.z = i1; iv.w = i2;

        y_in = __shfl(L, 63, 64);             // carry for next chunk

        const long ob = o0 + 4 * (long)lane;
        if constexpr (FAST) {
            __builtin_nontemporal_store(iv, reinterpret_cast<v4i*>(out + ob));
        } else {
            if (ob + 0 >= oLim) iv.x = 0;     // zero-pad tail outputs
            if (ob + 1 >= oLim) iv.y = 0;
            if (ob + 2 >= oLim) iv.z = 0;
            if (ob + 3 >= oLim) iv.w = 0;
            if (ob + 0 < ln) out[ob + 0] = iv.x;
            if (ob + 1 < ln) out[ob + 1] = iv.y;
            if (ob + 2 < ln) out[ob + 2] = iv.z;
            if (ob + 3 < ln) out[ob + 3] = iv.w;
        }
    }
}

__global__ __launch_bounds__(BLOCK, 8) void preemph_kernel(
        const float* __restrict__ sig, int* __restrict__ out, int n) {
    const long ln   = n;
    const int  lane = threadIdx.x & 63;
    const long segBase = (long)blockIdx.x * TILE + (long)(threadIdx.x >> 6) * SEG;
    if (segBase >= ln) return;

    // fast iff: warm reads >= 0  AND  loads end <= n  AND  no output zeroing.
    //   max read  = segBase + (SKIP+1) + SEG;  zeroing iff segBase+SEG > n-SKIP.
    const bool fast = (segBase >= 164) && (segBase + SEG + SKIP + 1 <= ln);
    if (fast) run_seg<true >(sig, out, segBase, ln, lane);
    else      run_seg<false>(sig, out, segBase, ln, lane);
}

extern "C" void kernel_launch(void* const* d_in, const int* in_sizes, int n_in,
                              void* d_out, int out_size, void* d_ws, size_t ws_size,
                              hipStream_t stream) {
    const float* sig = (const float*)d_in[0];
    int* out = (int*)d_out;
    int n = in_sizes[0];
    int grid = (int)(((long)n + TILE - 1) / TILE);
    preemph_kernel<<<grid, BLOCK, 0, stream>>>(sig, out, n);
}